// Round 21
// baseline (69.547 us; speedup 1.0000x reference)
//
#include <hip/hip_runtime.h>
#include <hip/hip_bf16.h>

typedef __bf16 bf16x8 __attribute__((ext_vector_type(8)));
typedef float  f32x4  __attribute__((ext_vector_type(4)));

#define B_ROWS 8192
#define IN_DIM 256
#define OUT_DIM 32
#define NCLS 50
#define INV_T (1.0f / 0.6f)

#define CVT_BLOCKS 1024  // x cvt: 8192*256 / (256*8)
#define ROWTILES 32      // 8192 / 256 rows per block
#define NH 8             // 64 rows/wave = 4 chunks = 8 half-K halves
#define OSTRIDE (NCLS * OUT_DIM)

__device__ __forceinline__ void gload_lds16(const void* g, void* l) {
    __builtin_amdgcn_global_load_lds(
        (const __attribute__((address_space(1))) void*)g,
        (__attribute__((address_space(3))) void*)l, 16, 0, 0);
}

// prep (r14 verbatim): blocks [0,50) W-class; blocks [50,1074) x cvt.
__global__ __launch_bounds__(256) void prep(const float* __restrict__ x,
                                            const float* __restrict__ w,
                                            __bf16* __restrict__ xb,
                                            __bf16* __restrict__ wb) {
    __shared__ float wm[4];
    int bid = blockIdx.x;
    if (bid < NCLS) {
        int c = bid;
        int i = threadIdx.x;
        const float* wc = w + (size_t)c * OUT_DIM * IN_DIM + i;
        float wv[OUT_DIM];
#pragma unroll
        for (int o = 0; o < OUT_DIM; ++o) wv[o] = wc[o * IN_DIM];
        float gsum = 0.f;
#pragma unroll
        for (int o = 0; o < OUT_DIM; ++o) gsum += fabsf(wv[o]);
        float m = gsum;
#pragma unroll
        for (int s = 1; s < 64; s <<= 1) m = fmaxf(m, __shfl_xor(m, s));
        if ((threadIdx.x & 63) == 0) wm[threadIdx.x >> 6] = m;
        __syncthreads();
        m = fmaxf(fmaxf(wm[0], wm[1]), fmaxf(wm[2], wm[3]));
        float an = __expf((gsum - m) * INV_T);
        __bf16* wo = wb + (size_t)c * OUT_DIM * IN_DIM + i;
#pragma unroll
        for (int o = 0; o < OUT_DIM; ++o)
            wo[o * IN_DIM] = (__bf16)(wv[o] * an);
    } else {
        int i = ((bid - NCLS) * 256 + threadIdx.x) * 8;
        float4 v0 = *reinterpret_cast<const float4*>(x + i);
        float4 v1 = *reinterpret_cast<const float4*>(x + i + 4);
        bf16x8 r;
        r[0] = (__bf16)v0.x; r[1] = (__bf16)v0.y; r[2] = (__bf16)v0.z; r[3] = (__bf16)v0.w;
        r[4] = (__bf16)v1.x; r[5] = (__bf16)v1.y; r[6] = (__bf16)v1.z; r[7] = (__bf16)v1.w;
        *reinterpret_cast<bf16x8*>(xb + i) = r;
    }
}

// GEMM — occupancy variant: out[b,c,o] = sum_i xb[b,i]*wb[c,o,i] + bias[c,o]
// grid = 25 class-pairs * 32 row-tiles = 800 (rt mod 8 -> XCD invariant).
// Block = 4 waves, 256 rows, 2 classes; wave = 64 rows = 8 half-K halves
// (16 rows x 128 K = 4 KB). 3 bufs/wave (12 KB) -> LDS 48 KB -> 3 blocks/CU;
// launch_bounds(256,3) caps VGPR at 170 (W 128 + bias 16 + acc 16 fits).
// Prefetch dist 2 (stage h+2 into buf (h+2)%3 — never the in-use buffer).
// Exact own-wave vmcnt (4 loads/iter; 4 stores after odd h):
//   h=0:8, h=1:8, h=2..5:12, h=6:8, h=7:4.
// 2 classes => 256 B contiguous store per row (full write granule, r20 lesson).
// Swizzles (both-sides): A 256B half-rows, phys slot p holds logical
// p^(rr&15); W 512B rows, phys s31 holds logical s31^(r&15).
__global__ __launch_bounds__(256, 3) void gemm(const __bf16* __restrict__ xb,
                                               const __bf16* __restrict__ wb,
                                               const float* __restrict__ bias,
                                               float* __restrict__ out) {
    __shared__ __align__(16) char lds[4 * 3 * 4096];  // 4 waves * 3 bufs * 4 KB

    int bid = blockIdx.x;
    int cp = bid >> 5;           // 0..24
    int rt = bid & (ROWTILES - 1);
    int c0 = cp * 2;
    int row0 = rt * 256;
    int lane = threadIdx.x & 63;
    int w4 = threadIdx.x >> 6;
    int l15 = lane & 15;
    int g = lane >> 4;           // 0..3
    int s31 = lane & 31;
    int lr = lane >> 5;

    char* wbase = lds + w4 * 12288;

    // --- stage W' pair (32 KB = 64 rows x 512 B) into lds[0..32K) linear ---
    const char* wsrc = (const char*)(wb + (size_t)c0 * OUT_DIM * IN_DIM);
#pragma unroll
    for (int jw = 0; jw < 8; ++jw) {
        int re = jw * 8 + w4 * 2;
        int r = re + lr;
        gload_lds16(wsrc + (size_t)r * 512 + ((s31 ^ (r & 15)) * 16),
                    lds + re * 512);
    }
    f32x4 bv00 = *reinterpret_cast<const f32x4*>(bias + c0 * OUT_DIM + g * 4);
    f32x4 bv01 = *reinterpret_cast<const f32x4*>(bias + c0 * OUT_DIM + 16 + g * 4);
    f32x4 bv10 = *reinterpret_cast<const f32x4*>(bias + (c0 + 1) * OUT_DIM + g * 4);
    f32x4 bv11 = *reinterpret_cast<const f32x4*>(bias + (c0 + 1) * OUT_DIM + 16 + g * 4);

    asm volatile("s_waitcnt vmcnt(0)" ::: "memory");
    __syncthreads();
    __builtin_amdgcn_sched_barrier(0);

    // --- W' -> 128 pinned VGPRs: W[ci][kk] o=l15, W[ci][8+kk] o=16+l15 ---
    bf16x8 W[2][16];
#pragma unroll
    for (int ci = 0; ci < 2; ++ci)
#pragma unroll
        for (int kk = 0; kk < 8; ++kk) {
            int slot = ((4 * kk + g) ^ l15) * 16;
            W[ci][kk]     = *reinterpret_cast<const bf16x8*>(
                lds + (size_t)(ci * 32 + l15) * 512 + slot);
            W[ci][8 + kk] = *reinterpret_cast<const bf16x8*>(
                lds + (size_t)(ci * 32 + 16 + l15) * 512 + slot);
        }
#pragma unroll
    for (int ci = 0; ci < 2; ++ci)
#pragma unroll
        for (int kk = 0; kk < 16; ++kk)
            asm volatile("" : "+v"(W[ci][kk]));
    asm volatile("" : "+v"(bv00), "+v"(bv01), "+v"(bv10), "+v"(bv11));
    __builtin_amdgcn_sched_barrier(0);
    __syncthreads();   // all waves done reading W before A staging overwrites

    // --- A half-K pipeline ---
    const char* arows = (const char*)(xb + (size_t)(row0 + w4 * 64) * IN_DIM);
    float* orow = out + (size_t)(row0 + w4 * 64 + l15) * OSTRIDE + c0 * OUT_DIM + g * 4;

    // half H: rows rr = (H>>1)*16 + j*4 + g, K-half (H&1); dst BUF + j*1024.
#define STAGE_H(BUF, H)                                                            \
    _Pragma("unroll") for (int j = 0; j < 4; ++j) {                                \
        int rr = ((H) >> 1) * 16 + j * 4 + g;                                      \
        gload_lds16(arows + (size_t)rr * 512 + ((H) & 1) * 256                     \
                        + ((l15 ^ (rr & 15)) * 16),                                \
                    (BUF) + j * 1024);                                             \
    }

    STAGE_H(wbase, 0)                       // buf 0
    STAGE_H(wbase + 4096, 1)                // buf 1

    f32x4 acc00, acc01, acc10, acc11;
#pragma unroll
    for (int h = 0; h < NH; ++h) {
        if (h <= NH - 3) {
            char* nbuf = wbase + ((h + 2) % 3) * 4096;
            STAGE_H(nbuf, h + 2)
        }
        if (h <= 1)      asm volatile("s_waitcnt vmcnt(8)" ::: "memory");
        else if (h <= 5) asm volatile("s_waitcnt vmcnt(12)" ::: "memory");
        else if (h == 6) asm volatile("s_waitcnt vmcnt(8)" ::: "memory");
        else             asm volatile("s_waitcnt vmcnt(4)" ::: "memory");
        __builtin_amdgcn_sched_barrier(0);

        if (!(h & 1)) { acc00 = bv00; acc01 = bv01; acc10 = bv10; acc11 = bv11; }
        const char* cb = wbase + (h % 3) * 4096;
        int h4 = (h & 1) * 4;
#pragma unroll
        for (int kkl = 0; kkl < 4; ++kkl) {
            bf16x8 a = *reinterpret_cast<const bf16x8*>(
                cb + (size_t)l15 * 256 + (((4 * kkl + g) ^ l15) * 16));
            acc00 = __builtin_amdgcn_mfma_f32_16x16x32_bf16(W[0][h4 + kkl],     a, acc00, 0, 0, 0);
            acc01 = __builtin_amdgcn_mfma_f32_16x16x32_bf16(W[0][8 + h4 + kkl], a, acc01, 0, 0, 0);
            acc10 = __builtin_amdgcn_mfma_f32_16x16x32_bf16(W[1][h4 + kkl],     a, acc10, 0, 0, 0);
            acc11 = __builtin_amdgcn_mfma_f32_16x16x32_bf16(W[1][8 + h4 + kkl], a, acc11, 0, 0, 0);
        }
        if (h & 1) {
            float* op = orow + (size_t)(h >> 1) * 16 * OSTRIDE;
            *reinterpret_cast<f32x4*>(op) = acc00;
            *reinterpret_cast<f32x4*>(op + 16) = acc01;
            *reinterpret_cast<f32x4*>(op + OUT_DIM) = acc10;
            *reinterpret_cast<f32x4*>(op + OUT_DIM + 16) = acc11;
        }
    }
#undef STAGE_H
}

extern "C" void kernel_launch(void* const* d_in, const int* in_sizes, int n_in,
                              void* d_out, int out_size, void* d_ws, size_t ws_size,
                              hipStream_t stream) {
    const float* x    = (const float*)d_in[0];
    const float* w    = (const float*)d_in[1];
    const float* bias = (const float*)d_in[2];
    float* out = (float*)d_out;

    __bf16* xb = (__bf16*)d_ws;                      // 8192*256 bf16 = 4 MB
    __bf16* wb = xb + (size_t)B_ROWS * IN_DIM;       // 50*32*256 bf16 = 0.8 MB

    prep<<<NCLS + CVT_BLOCKS, 256, 0, stream>>>(x, w, xb, wb);
    gemm<<<25 * ROWTILES, 256, 0, stream>>>(xb, wb, bias, out);
}

// Round 22
// 28.184 us; speedup vs baseline: 2.4676x; 2.4676x over previous
//
#include <hip/hip_runtime.h>
#include <hip/hip_bf16.h>

typedef __bf16 bf16x8 __attribute__((ext_vector_type(8)));
typedef float  f32x4  __attribute__((ext_vector_type(4)));

#define B_ROWS 8192
#define IN_DIM 256
#define OUT_DIM 32
#define NCLS 50
#define INV_T (1.0f / 0.6f)

#define CVT_BLOCKS 1024  // x cvt: 8192*256 / (256*8)
#define ROWTILES 16      // 8192 / 512 rows per block
#define NCHUNK 8         // 128 rows/wave / 16

__device__ __forceinline__ void gload_lds16(const void* g, void* l) {
    __builtin_amdgcn_global_load_lds(
        (const __attribute__((address_space(1))) void*)g,
        (__attribute__((address_space(3))) void*)l, 16, 0, 0);
}

// prep (r14 verbatim): blocks [0,50) W-class; blocks [50,1074) x cvt.
__global__ __launch_bounds__(256) void prep(const float* __restrict__ x,
                                            const float* __restrict__ w,
                                            __bf16* __restrict__ xb,
                                            __bf16* __restrict__ wb) {
    __shared__ float wm[4];
    int bid = blockIdx.x;
    if (bid < NCLS) {
        int c = bid;
        int i = threadIdx.x;  // IN index
        const float* wc = w + (size_t)c * OUT_DIM * IN_DIM + i;
        float wv[OUT_DIM];
#pragma unroll
        for (int o = 0; o < OUT_DIM; ++o) wv[o] = wc[o * IN_DIM];
        float gsum = 0.f;
#pragma unroll
        for (int o = 0; o < OUT_DIM; ++o) gsum += fabsf(wv[o]);
        float m = gsum;
#pragma unroll
        for (int s = 1; s < 64; s <<= 1) m = fmaxf(m, __shfl_xor(m, s));
        if ((threadIdx.x & 63) == 0) wm[threadIdx.x >> 6] = m;
        __syncthreads();
        m = fmaxf(fmaxf(wm[0], wm[1]), fmaxf(wm[2], wm[3]));
        float an = __expf((gsum - m) * INV_T);
        __bf16* wo = wb + (size_t)c * OUT_DIM * IN_DIM + i;
#pragma unroll
        for (int o = 0; o < OUT_DIM; ++o)
            wo[o * IN_DIM] = (__bf16)(wv[o] * an);
    } else {
        int i = ((bid - NCLS) * 256 + threadIdx.x) * 8;
        float4 v0 = *reinterpret_cast<const float4*>(x + i);
        float4 v1 = *reinterpret_cast<const float4*>(x + i + 4);
        bf16x8 r;
        r[0] = (__bf16)v0.x; r[1] = (__bf16)v0.y; r[2] = (__bf16)v0.z; r[3] = (__bf16)v0.w;
        r[4] = (__bf16)v1.x; r[5] = (__bf16)v1.y; r[6] = (__bf16)v1.z; r[7] = (__bf16)v1.w;
        *reinterpret_cast<bf16x8*>(xb + i) = r;
    }
}

// GEMM (r14 body; grid REMAPPED for XCD write-locality):
// out[b, c, o] = sum_i xb[b,i]*wb[c,o,i] + bias[c,o]
// bid = cp*8 + (rt mod 8) + (rt div 8)*200  =>  bid mod 8 = rt mod 8:
// all 25 class-pairs of one row-tile share an XCD and are co-resident, so
// the XCD's L2 assembles the 25 x 256B column-stripes of each output row
// into full lines before HBM eviction (near-sequential write stream), and
// same-rt blocks share their A-slice in L2.
// Block = 4 waves, 512 rows, 2 classes; W' slab staged into the Abuf1
// union; 128 pinned VGPRs; counted vmcnt(12) pipeline (r14 verbatim).
__global__ __launch_bounds__(256, 2) void gemm(const __bf16* __restrict__ xb,
                                               const __bf16* __restrict__ wb,
                                               const float* __restrict__ bias,
                                               float* __restrict__ out) {
    __shared__ __align__(16) char lds[4 * 2 * 8192];  // 4 waves * {Abuf0, Abuf1}

    int bid = blockIdx.x;
    int half = bid / 200;                // 0/1
    int rem  = bid - half * 200;         // 0..199
    int cp   = rem >> 3;                 // 0..24
    int rt   = (rem & 7) + half * 8;     // 0..15
    int c0 = cp * 2;
    int row0 = rt * 512;
    int lane = threadIdx.x & 63;
    int w4 = threadIdx.x >> 6;
    int l15 = lane & 15;
    int g = lane >> 4;
    int s31 = lane & 31;
    int lr = lane >> 5;          // 0/1

    char* Abuf0 = lds + w4 * 16384;
    char* Abuf1 = Abuf0 + 8192;

    // --- stage A chunk 0 (wave-private 16 rows = 8 KB) into Abuf0 ---
    const char* arows = (const char*)(xb + (size_t)(row0 + w4 * 128) * IN_DIM);
#define STAGE_A(BUF, CHUNK)                                                       \
    _Pragma("unroll") for (int il = 0; il < 8; ++il) {                            \
        int r = (CHUNK) * 16 + 2 * il + lr;                                       \
        gload_lds16(arows + (size_t)r * 512 + ((s31 ^ (r & 15)) * 16),            \
                    (BUF) + il * 1024);                                           \
    }
    STAGE_A(Abuf0, 0)

    // --- stage W' pair (32 KB = 64 rows) into the Abuf1 regions ---
    const char* wsrc = (const char*)(wb + (size_t)c0 * OUT_DIM * IN_DIM);
#pragma unroll
    for (int jw = 0; jw < 8; ++jw) {
        int re = jw * 8 + w4 * 2;              // even row of this instr
        int r = re + lr;
        gload_lds16(wsrc + (size_t)r * 512 + ((s31 ^ (r & 15)) * 16),
                    lds + (re >> 4) * 16384 + 8192 + (re & 15) * 512);
    }

    asm volatile("s_waitcnt vmcnt(0)" ::: "memory");
    __syncthreads();
    __builtin_amdgcn_sched_barrier(0);

    // --- W' -> regs (swizzled ds_read); W row = ci*32 + l15 (+16) ---
    bf16x8 W[2][16];
#pragma unroll
    for (int ci = 0; ci < 2; ++ci)
#pragma unroll
        for (int kk = 0; kk < 8; ++kk) {
            int slot = (4 * kk + g) ^ l15;
            W[ci][kk]     = *reinterpret_cast<const bf16x8*>(
                lds + (2 * ci) * 16384 + 8192 + l15 * 512 + slot * 16);
            W[ci][8 + kk] = *reinterpret_cast<const bf16x8*>(
                lds + (2 * ci + 1) * 16384 + 8192 + l15 * 512 + slot * 16);
        }
#pragma unroll
    for (int ci = 0; ci < 2; ++ci)
#pragma unroll
        for (int kk = 0; kk < 16; ++kk)
            asm volatile("" : "+v"(W[ci][kk]));
    __builtin_amdgcn_sched_barrier(0);
    __syncthreads();   // all waves done reading W before chunk 1 stages Abuf1

    f32x4 bv00 = *reinterpret_cast<const f32x4*>(bias + c0 * OUT_DIM + g * 4);
    f32x4 bv01 = *reinterpret_cast<const f32x4*>(bias + c0 * OUT_DIM + 16 + g * 4);
    f32x4 bv10 = *reinterpret_cast<const f32x4*>(bias + (c0 + 1) * OUT_DIM + g * 4);
    f32x4 bv11 = *reinterpret_cast<const f32x4*>(bias + (c0 + 1) * OUT_DIM + 16 + g * 4);

    float* orow = out + (size_t)(row0 + w4 * 128 + l15) * (NCLS * OUT_DIM) + c0 * OUT_DIM + g * 4;

    // --- main loop: 8 chunks of 16 rows, 2 classes each ---
#pragma unroll
    for (int k = 0; k < NCHUNK; ++k) {
        char* cur = (k & 1) ? Abuf1 : Abuf0;
        char* nxt = (k & 1) ? Abuf0 : Abuf1;
        if (k + 1 < NCHUNK) {
            STAGE_A(nxt, k + 1)
            asm volatile("s_waitcnt vmcnt(12)" ::: "memory");
        } else {
            asm volatile("s_waitcnt vmcnt(4)" ::: "memory");
        }
        __builtin_amdgcn_sched_barrier(0);

        f32x4 acc00 = bv00;
        f32x4 acc01 = bv01;
        f32x4 acc10 = bv10;
        f32x4 acc11 = bv11;
#pragma unroll
        for (int kk = 0; kk < 8; ++kk) {
            int slot = (4 * kk + g) ^ l15;
            bf16x8 a = *reinterpret_cast<const bf16x8*>(cur + (size_t)l15 * 512 + slot * 16);
            acc00 = __builtin_amdgcn_mfma_f32_16x16x32_bf16(W[0][kk],     a, acc00, 0, 0, 0);
            acc01 = __builtin_amdgcn_mfma_f32_16x16x32_bf16(W[0][8 + kk], a, acc01, 0, 0, 0);
            acc10 = __builtin_amdgcn_mfma_f32_16x16x32_bf16(W[1][kk],     a, acc10, 0, 0, 0);
            acc11 = __builtin_amdgcn_mfma_f32_16x16x32_bf16(W[1][8 + kk], a, acc11, 0, 0, 0);
        }
        float* op = orow + (size_t)k * 16 * (NCLS * OUT_DIM);
        *reinterpret_cast<f32x4*>(op) = acc00;
        *reinterpret_cast<f32x4*>(op + 16) = acc01;
        *reinterpret_cast<f32x4*>(op + OUT_DIM) = acc10;
        *reinterpret_cast<f32x4*>(op + OUT_DIM + 16) = acc11;
    }
#undef STAGE_A
}

extern "C" void kernel_launch(void* const* d_in, const int* in_sizes, int n_in,
                              void* d_out, int out_size, void* d_ws, size_t ws_size,
                              hipStream_t stream) {
    const float* x    = (const float*)d_in[0];
    const float* w    = (const float*)d_in[1];
    const float* bias = (const float*)d_in[2];
    float* out = (float*)d_out;

    __bf16* xb = (__bf16*)d_ws;                      // 8192*256 bf16 = 4 MB
    __bf16* wb = xb + (size_t)B_ROWS * IN_DIM;       // 50*32*256 bf16 = 0.8 MB

    prep<<<NCLS + CVT_BLOCKS, 256, 0, stream>>>(x, w, xb, wb);
    gemm<<<25 * ROWTILES, 256, 0, stream>>>(xb, wb, bias, out);
}